// Round 14
// baseline (75.446 us; speedup 1.0000x reference)
//
#include <hip/hip_runtime.h>
#include <hip/hip_fp16.h>

#define EMB 128
#define KN 16
#define NREL 32

__device__ __forceinline__ float fast_tanh(float x) {
    // exact identity tanh(x) = 1 - 2/(e^{2x}+1); v_exp-based, ~1e-6 abs err.
    const float z = __expf(2.0f * x);
    return 1.0f - __fdividef(2.0f, z + 1.0f);
}

__device__ __forceinline__ float4 fma4(float s, float4 v, float4 a) {
    a.x = fmaf(s, v.x, a.x); a.y = fmaf(s, v.y, a.y);
    a.z = fmaf(s, v.z, a.z); a.w = fmaf(s, v.w, a.w);
    return a;
}

// non-temporal half2 load: skip L1 allocation (no per-CU reuse of rows)
__device__ __forceinline__ __half2 ldnt_h2(const __half2* p) {
    union { unsigned u; __half2 h; } c;
    c.u = __builtin_nontemporal_load((const unsigned*)p);
    return c.h;
}

// ---------------- prep: role-split grid (verified r13) ----------------------
// blocks [0,256): costab (4 pairs/block = 1024 pairs)
// blocks [256,..): node_table fp32 -> fp16 grid-stride convert
__global__ __launch_bounds__(256) void pgra_prep(
    const float* __restrict__ node_table, __half* __restrict__ nt16, int n8,
    const float* __restrict__ rela, float* __restrict__ costab)
{
    if (blockIdx.x < 256) {
        const int pair = blockIdx.x * 4 + (threadIdx.x >> 6);
        const int lane = threadIdx.x & 63;
        const int r = pair >> 5, c = pair & 31;
        const float2 av = ((const float2*)(rela + (size_t)r * EMB))[lane];
        const float2 bv = ((const float2*)(rela + (size_t)c * EMB))[lane];
        float dot = av.x * bv.x + av.y * bv.y;
        float na  = av.x * av.x + av.y * av.y;
        float nb  = bv.x * bv.x + bv.y * bv.y;
        #pragma unroll
        for (int off = 32; off > 0; off >>= 1) {
            dot += __shfl_xor(dot, off);
            na  += __shfl_xor(na,  off);
            nb  += __shfl_xor(nb,  off);
        }
        if (lane == 0)
            costab[pair] = fabsf(dot / (sqrtf(na) * sqrtf(nb) + 1e-8f));
        return;
    }
    union { __half2 h; unsigned u; } c0, c1, c2, c3;
    const int stride = (gridDim.x - 256) * 256;
    for (int i = (blockIdx.x - 256) * 256 + threadIdx.x; i < n8; i += stride) {
        const float4 a = ((const float4*)node_table)[2 * i];
        const float4 b = ((const float4*)node_table)[2 * i + 1];
        c0.h = __float22half2_rn(make_float2(a.x, a.y));
        c1.h = __float22half2_rn(make_float2(a.z, a.w));
        c2.h = __float22half2_rn(make_float2(b.x, b.y));
        c3.h = __float22half2_rn(make_float2(b.z, b.w));
        uint4 o; o.x = c0.u; o.y = c1.u; o.z = c2.u; o.w = c3.u;
        ((uint4*)nt16)[i] = o;
    }
}

// ---------------- Kernel A: fp16 gather, one (b,j) per wave, NT loads -------
// r12-verified structure; rows loaded non-temporally (no L1 allocation).
__global__ __launch_bounds__(256) void pgra_gather7(
    const int* __restrict__ node, const int* __restrict__ relation,
    const int* __restrict__ adj_node, const int* __restrict__ adj_rela,
    const __half* __restrict__ nt16, const float* __restrict__ proj_table,
    const float* __restrict__ costab, float* __restrict__ agg, int npair)
{
    const int p = blockIdx.x * 4 + (threadIdx.x >> 6);
    if (p >= npair) return;
    const int lane = threadIdx.x & 63;
    const int b = p >> 4, j = p & 15;

    const int n0  = node[b];
    const int rel = relation[b];
    const int n1  = adj_node[n0 * KN + j];

    const int4* n2p = (const int4*)(adj_node + (size_t)n1 * KN);
    const int4* r1p = (const int4*)(adj_rela + (size_t)n1 * KN);
    const int4 nn0 = n2p[0], nn1 = n2p[1], nn2 = n2p[2], nn3 = n2p[3];
    const int4 rr0 = r1p[0], rr1 = r1p[1], rr2 = r1p[2], rr3 = r1p[3];

    // ---- issue all 16 row loads (half2/lane, non-temporal) ----
    __half2 h0,h1,h2,h3,h4,h5,h6,h7,h8,h9,h10,h11,h12,h13,h14,h15;
    h0  = ldnt_h2(((const __half2*)(nt16 + (size_t)nn0.x * EMB)) + lane);
    h1  = ldnt_h2(((const __half2*)(nt16 + (size_t)nn0.y * EMB)) + lane);
    h2  = ldnt_h2(((const __half2*)(nt16 + (size_t)nn0.z * EMB)) + lane);
    h3  = ldnt_h2(((const __half2*)(nt16 + (size_t)nn0.w * EMB)) + lane);
    h4  = ldnt_h2(((const __half2*)(nt16 + (size_t)nn1.x * EMB)) + lane);
    h5  = ldnt_h2(((const __half2*)(nt16 + (size_t)nn1.y * EMB)) + lane);
    h6  = ldnt_h2(((const __half2*)(nt16 + (size_t)nn1.z * EMB)) + lane);
    h7  = ldnt_h2(((const __half2*)(nt16 + (size_t)nn1.w * EMB)) + lane);
    h8  = ldnt_h2(((const __half2*)(nt16 + (size_t)nn2.x * EMB)) + lane);
    h9  = ldnt_h2(((const __half2*)(nt16 + (size_t)nn2.y * EMB)) + lane);
    h10 = ldnt_h2(((const __half2*)(nt16 + (size_t)nn2.z * EMB)) + lane);
    h11 = ldnt_h2(((const __half2*)(nt16 + (size_t)nn2.w * EMB)) + lane);
    h12 = ldnt_h2(((const __half2*)(nt16 + (size_t)nn3.x * EMB)) + lane);
    h13 = ldnt_h2(((const __half2*)(nt16 + (size_t)nn3.y * EMB)) + lane);
    h14 = ldnt_h2(((const __half2*)(nt16 + (size_t)nn3.z * EMB)) + lane);
    h15 = ldnt_h2(((const __half2*)(nt16 + (size_t)nn3.w * EMB)) + lane);
    __builtin_amdgcn_sched_barrier(0);

    // ---- scores + softmax while the row loads are in flight ----
    float sc[KN];
    sc[0]  = costab[rr0.x * NREL + rel]; sc[1]  = costab[rr0.y * NREL + rel];
    sc[2]  = costab[rr0.z * NREL + rel]; sc[3]  = costab[rr0.w * NREL + rel];
    sc[4]  = costab[rr1.x * NREL + rel]; sc[5]  = costab[rr1.y * NREL + rel];
    sc[6]  = costab[rr1.z * NREL + rel]; sc[7]  = costab[rr1.w * NREL + rel];
    sc[8]  = costab[rr2.x * NREL + rel]; sc[9]  = costab[rr2.y * NREL + rel];
    sc[10] = costab[rr2.z * NREL + rel]; sc[11] = costab[rr2.w * NREL + rel];
    sc[12] = costab[rr3.x * NREL + rel]; sc[13] = costab[rr3.y * NREL + rel];
    sc[14] = costab[rr3.z * NREL + rel]; sc[15] = costab[rr3.w * NREL + rel];

    float m = sc[0];
    #pragma unroll
    for (int k = 1; k < KN; ++k) m = fmaxf(m, sc[k]);
    float sum = 0.f;
    #pragma unroll
    for (int k = 0; k < KN; ++k) { sc[k] = __expf(sc[k] - m); sum += sc[k]; }
    const float inv = __fdividef(1.f, sum);

    // ---- weighted sum over prefetched rows ----
    float ax = 0.f, ay = 0.f;
    float2 v;
    v = __half22float2(h0);  ax = fmaf(sc[0],  v.x, ax); ay = fmaf(sc[0],  v.y, ay);
    v = __half22float2(h1);  ax = fmaf(sc[1],  v.x, ax); ay = fmaf(sc[1],  v.y, ay);
    v = __half22float2(h2);  ax = fmaf(sc[2],  v.x, ax); ay = fmaf(sc[2],  v.y, ay);
    v = __half22float2(h3);  ax = fmaf(sc[3],  v.x, ax); ay = fmaf(sc[3],  v.y, ay);
    v = __half22float2(h4);  ax = fmaf(sc[4],  v.x, ax); ay = fmaf(sc[4],  v.y, ay);
    v = __half22float2(h5);  ax = fmaf(sc[5],  v.x, ax); ay = fmaf(sc[5],  v.y, ay);
    v = __half22float2(h6);  ax = fmaf(sc[6],  v.x, ax); ay = fmaf(sc[6],  v.y, ay);
    v = __half22float2(h7);  ax = fmaf(sc[7],  v.x, ax); ay = fmaf(sc[7],  v.y, ay);
    v = __half22float2(h8);  ax = fmaf(sc[8],  v.x, ax); ay = fmaf(sc[8],  v.y, ay);
    v = __half22float2(h9);  ax = fmaf(sc[9],  v.x, ax); ay = fmaf(sc[9],  v.y, ay);
    v = __half22float2(h10); ax = fmaf(sc[10], v.x, ax); ay = fmaf(sc[10], v.y, ay);
    v = __half22float2(h11); ax = fmaf(sc[11], v.x, ax); ay = fmaf(sc[11], v.y, ay);
    v = __half22float2(h12); ax = fmaf(sc[12], v.x, ax); ay = fmaf(sc[12], v.y, ay);
    v = __half22float2(h13); ax = fmaf(sc[13], v.x, ax); ay = fmaf(sc[13], v.y, ay);
    v = __half22float2(h14); ax = fmaf(sc[14], v.x, ax); ay = fmaf(sc[14], v.y, ay);
    v = __half22float2(h15); ax = fmaf(sc[15], v.x, ax); ay = fmaf(sc[15], v.y, ay);

    const float2 pj = ((const float2*)(proj_table + (size_t)rel * EMB))[lane];
    float2 o;
    o.x = ax * inv * pj.x;
    o.y = ay * inv * pj.y;
    ((float2*)(agg + (size_t)p * EMB))[lane] = o;
}

// ---------------- Kernel B: tail11 (r11/r12 verified, half-wave k-split) ----
__global__ __launch_bounds__(256) void pgra_tail11(
    const int* __restrict__ node, const int* __restrict__ relation,
    const int* __restrict__ adj_rela, const float* __restrict__ agg,
    const float* __restrict__ W0, const float* __restrict__ b0,
    const float* __restrict__ W1, const float* __restrict__ b1,
    const float* __restrict__ costab, float* __restrict__ out)
{
    const int blk  = blockIdx.x;
    const int tid  = threadIdx.x;
    const int wave = tid >> 6;
    const int lane = tid & 63;
    const int h    = lane >> 5;
    const int c    = lane & 31;
    const int b    = blk * 4 + wave;

    __shared__ float s_agg[4][KN][EMB];
    __shared__ float s_fin[4][EMB];

    {
        const float4* ap = (const float4*)(agg + (size_t)blk * 4 * KN * EMB);
        float4* sp = (float4*)&s_agg[0][0][0];
        #pragma unroll
        for (int q = 0; q < 8; ++q) sp[tid + 256 * q] = ap[tid + 256 * q];
    }

    const int n0  = node[b];
    const int rel = relation[b];

    float sc0[KN];
    {
        const int4* r0p = (const int4*)(adj_rela + (size_t)n0 * KN);
        #pragma unroll
        for (int q = 0; q < 4; ++q) {
            const int4 rr = r0p[q];
            sc0[4*q+0] = costab[rr.x * NREL + rel];
            sc0[4*q+1] = costab[rr.y * NREL + rel];
            sc0[4*q+2] = costab[rr.z * NREL + rel];
            sc0[4*q+3] = costab[rr.w * NREL + rel];
        }
    }
    float m = sc0[0];
    #pragma unroll
    for (int k = 1; k < KN; ++k) m = fmaxf(m, sc0[k]);
    float sum = 0.f;
    #pragma unroll
    for (int k = 0; k < KN; ++k) { sc0[k] = __expf(sc0[k] - m); sum += sc0[k]; }
    const float inv = __fdividef(1.f, sum);

    __syncthreads();

    float4 acc[8];
    const float4 bias = *(const float4*)&b0[4 * c];
    #pragma unroll
    for (int kk = 0; kk < 8; ++kk) acc[kk] = bias;

    for (int ee4 = 0; ee4 < 32; ++ee4) {
        const int row = 4 * ee4;
        float4 w0q[4];
        #pragma unroll
        for (int r = 0; r < 4; ++r)
            w0q[r] = *(const float4*)&W0[(row + r) * EMB + 4 * c];
        #pragma unroll
        for (int kk = 0; kk < 8; ++kk) {
            const float4 a = *(const float4*)&s_agg[wave][8 * h + kk][row];
            acc[kk] = fma4(a.x, w0q[0], fma4(a.y, w0q[1],
                      fma4(a.z, w0q[2], fma4(a.w, w0q[3], acc[kk]))));
        }
    }

    float4 part = make_float4(0.f, 0.f, 0.f, 0.f);
    #pragma unroll
    for (int kk = 0; kk < 8; ++kk) {
        const float w = sc0[8 * h + kk] * inv;
        part.x = fmaf(w, fast_tanh(acc[kk].x), part.x);
        part.y = fmaf(w, fast_tanh(acc[kk].y), part.y);
        part.z = fmaf(w, fast_tanh(acc[kk].z), part.z);
        part.w = fmaf(w, fast_tanh(acc[kk].w), part.w);
    }
    part.x += __shfl_xor(part.x, 32);
    part.y += __shfl_xor(part.y, 32);
    part.z += __shfl_xor(part.z, 32);
    part.w += __shfl_xor(part.w, 32);
    if (h == 0) *(float4*)&s_fin[wave][4 * c] = part;
    __syncthreads();

    float4 o = make_float4(0.f, 0.f, 0.f, 0.f);
    for (int i = 0; i < 16; ++i) {
        const int row = 64 * h + 4 * i;
        const float4 f = *(const float4*)&s_fin[wave][row];
        float4 w1q[4];
        #pragma unroll
        for (int r = 0; r < 4; ++r)
            w1q[r] = *(const float4*)&W1[(row + r) * EMB + 4 * c];
        o = fma4(f.x, w1q[0], fma4(f.y, w1q[1],
            fma4(f.z, w1q[2], fma4(f.w, w1q[3], o))));
    }
    o.x += __shfl_xor(o.x, 32);
    o.y += __shfl_xor(o.y, 32);
    o.z += __shfl_xor(o.z, 32);
    o.w += __shfl_xor(o.w, 32);
    if (h == 0) {
        const float4 bb = *(const float4*)&b1[4 * c];
        float4 r;
        r.x = fast_tanh(o.x + bb.x);
        r.y = fast_tanh(o.y + bb.y);
        r.z = fast_tanh(o.z + bb.z);
        r.w = fast_tanh(o.w + bb.w);
        *(float4*)&out[(size_t)b * EMB + 4 * c] = r;
    }
}

// ---------------- Fallback: standalone costab + fused fp32 (verified) -------
__global__ __launch_bounds__(256) void pgra_costab_k(const float* __restrict__ rela,
                                                     float* __restrict__ costab) {
    const int pair = blockIdx.x * 4 + (threadIdx.x >> 6);
    const int lane = threadIdx.x & 63;
    const int r = pair >> 5, c = pair & 31;
    const float2 av = ((const float2*)(rela + (size_t)r * EMB))[lane];
    const float2 bv = ((const float2*)(rela + (size_t)c * EMB))[lane];
    float dot = av.x * bv.x + av.y * bv.y;
    float na  = av.x * av.x + av.y * av.y;
    float nb  = bv.x * bv.x + bv.y * bv.y;
    #pragma unroll
    for (int off = 32; off > 0; off >>= 1) {
        dot += __shfl_xor(dot, off);
        na  += __shfl_xor(na,  off);
        nb  += __shfl_xor(nb,  off);
    }
    if (lane == 0)
        costab[pair] = fabsf(dot / (sqrtf(na) * sqrtf(nb) + 1e-8f));
}

__global__ __launch_bounds__(1024) void pgra_fused(
    const int* __restrict__ node, const int* __restrict__ relation,
    const int* __restrict__ adj_node, const int* __restrict__ adj_rela,
    const float* __restrict__ node_table, const float* __restrict__ proj_table,
    const float* __restrict__ W0, const float* __restrict__ b0,
    const float* __restrict__ W1, const float* __restrict__ b1,
    const float* __restrict__ costab, float* __restrict__ out)
{
    const int b    = blockIdx.x;
    const int tid  = threadIdx.x;
    const int wave = tid >> 6;
    const int lane = tid & 63;

    __shared__ float s_agg[KN][EMB];
    __shared__ float s_part[2][EMB];
    __shared__ float s_fin[EMB];

    const int n0  = node[b];
    const int rel = relation[b];

    {
        const int j  = wave;
        const int n1 = adj_node[n0 * KN + j];
        const int4* n2p = (const int4*)(adj_node + (size_t)n1 * KN);
        const int4* r1p = (const int4*)(adj_rela + (size_t)n1 * KN);
        int   n2[KN];
        float sc[KN];
        #pragma unroll
        for (int q = 0; q < 4; ++q) {
            const int4 nn = n2p[q];
            const int4 rr = r1p[q];
            n2[4*q+0] = nn.x; n2[4*q+1] = nn.y; n2[4*q+2] = nn.z; n2[4*q+3] = nn.w;
            sc[4*q+0] = costab[rr.x * NREL + rel];
            sc[4*q+1] = costab[rr.y * NREL + rel];
            sc[4*q+2] = costab[rr.z * NREL + rel];
            sc[4*q+3] = costab[rr.w * NREL + rel];
        }
        float m = sc[0];
        #pragma unroll
        for (int k = 1; k < KN; ++k) m = fmaxf(m, sc[k]);
        float sum = 0.f;
        #pragma unroll
        for (int k = 0; k < KN; ++k) { sc[k] = __expf(sc[k] - m); sum += sc[k]; }
        const float inv = 1.f / sum;
        float ax = 0.f, ay = 0.f;
        #pragma unroll
        for (int k = 0; k < KN; ++k) {
            const float2 v = ((const float2*)(node_table + (size_t)n2[k] * EMB))[lane];
            ax = fmaf(sc[k], v.x, ax);
            ay = fmaf(sc[k], v.y, ay);
        }
        const float2 pj = ((const float2*)(proj_table + (size_t)rel * EMB))[lane];
        s_agg[j][2*lane]   = ax * inv * pj.x;
        s_agg[j][2*lane+1] = ay * inv * pj.y;
    }
    __syncthreads();

    if (tid < 256) {
        const int e  = tid & 127;
        const int g  = tid >> 7;
        const int jg = g * 8;
        float acc[8];
        const float bias = b0[e];
        #pragma unroll
        for (int q = 0; q < 8; ++q) acc[q] = bias;
        for (int ee4 = 0; ee4 < EMB / 4; ++ee4) {
            const float w0v = W0[(4 * ee4 + 0) * EMB + e];
            const float w1v = W0[(4 * ee4 + 1) * EMB + e];
            const float w2v = W0[(4 * ee4 + 2) * EMB + e];
            const float w3v = W0[(4 * ee4 + 3) * EMB + e];
            #pragma unroll
            for (int q = 0; q < 8; ++q) {
                const float4 a = *(const float4*)&s_agg[jg + q][4 * ee4];
                acc[q] = fmaf(a.x, w0v, fmaf(a.y, w1v, fmaf(a.z, w2v, fmaf(a.w, w3v, acc[q]))));
            }
        }
        float sc0[KN];
        float m = -1e30f;
        #pragma unroll
        for (int k = 0; k < KN; ++k) {
            sc0[k] = costab[adj_rela[n0 * KN + k] * NREL + rel];
            m = fmaxf(m, sc0[k]);
        }
        float sum = 0.f;
        #pragma unroll
        for (int k = 0; k < KN; ++k) { sc0[k] = __expf(sc0[k] - m); sum += sc0[k]; }
        const float inv = 1.f / sum;
        float part = 0.f;
        #pragma unroll
        for (int q = 0; q < 8; ++q)
            part = fmaf(sc0[jg + q] * inv, fast_tanh(acc[q]), part);
        s_part[g][e] = part;
    }
    __syncthreads();

    if (tid < EMB) s_fin[tid] = s_part[0][tid] + s_part[1][tid];
    __syncthreads();

    if (tid < EMB) {
        float acc = b1[tid];
        for (int ee = 0; ee < EMB; ++ee) acc = fmaf(s_fin[ee], W1[ee * EMB + tid], acc);
        out[(size_t)b * EMB + tid] = fast_tanh(acc);
    }
}

extern "C" void kernel_launch(void* const* d_in, const int* in_sizes, int n_in,
                              void* d_out, int out_size, void* d_ws, size_t ws_size,
                              hipStream_t stream) {
    const int*   node       = (const int*)d_in[0];
    const int*   relation   = (const int*)d_in[1];
    const int*   adj_node   = (const int*)d_in[2];
    const int*   adj_rela   = (const int*)d_in[3];
    const float* node_table = (const float*)d_in[4];
    const float* rela_table = (const float*)d_in[5];
    const float* proj_table = (const float*)d_in[6];
    const float* W0         = (const float*)d_in[7];
    const float* b0         = (const float*)d_in[8];
    const float* W1         = (const float*)d_in[9];
    const float* b1         = (const float*)d_in[10];
    float* outp = (float*)d_out;
    const int B  = in_sizes[0];
    const int NN = in_sizes[4] / EMB;

    float*  costab = (float*)d_ws;                          // 4 KB
    float*  agg    = (float*)d_ws + 1024;                   // B*16*128 fp32
    __half* nt16   = (__half*)(agg + (size_t)B * KN * EMB); // NN*128 fp16

    const size_t need = (size_t)(1024 + (size_t)B * KN * EMB) * sizeof(float)
                      + (size_t)NN * EMB * sizeof(__half);

    if (ws_size >= need && (B % 4) == 0) {
        const int n8 = NN * EMB / 8;
        hipLaunchKernelGGL(pgra_prep, dim3(256 + 2048), dim3(256), 0, stream,
                           node_table, nt16, n8, rela_table, costab);
        const int npair = B * KN;
        hipLaunchKernelGGL(pgra_gather7, dim3((npair + 3) / 4), dim3(256), 0, stream,
                           node, relation, adj_node, adj_rela,
                           nt16, proj_table, costab, agg, npair);
        hipLaunchKernelGGL(pgra_tail11, dim3(B / 4), dim3(256), 0, stream,
                           node, relation, adj_rela, agg,
                           W0, b0, W1, b1, costab, outp);
    } else {
        hipLaunchKernelGGL(pgra_costab_k, dim3(NREL * NREL / 4), dim3(256), 0, stream,
                           rela_table, costab);
        hipLaunchKernelGGL(pgra_fused, dim3(B), dim3(1024), 0, stream,
                           node, relation, adj_node, adj_rela,
                           node_table, proj_table, W0, b0, W1, b1, costab, outp);
    }
}

// Round 15
// 65.346 us; speedup vs baseline: 1.1546x; 1.1546x over previous
//
#include <hip/hip_runtime.h>
#include <hip/hip_fp16.h>

#define EMB 128
#define KN 16
#define NREL 32

__device__ __forceinline__ float fast_tanh(float x) {
    // exact identity tanh(x) = 1 - 2/(e^{2x}+1); v_exp-based, ~1e-6 abs err.
    const float z = __expf(2.0f * x);
    return 1.0f - __fdividef(2.0f, z + 1.0f);
}

__device__ __forceinline__ float4 fma4(float s, float4 v, float4 a) {
    a.x = fmaf(s, v.x, a.x); a.y = fmaf(s, v.y, a.y);
    a.z = fmaf(s, v.z, a.z); a.w = fmaf(s, v.w, a.w);
    return a;
}

// ---------------- prep: role-split grid (verified r13/r14) ------------------
// blocks [0,256): costab (4 pairs/block = 1024 pairs)
// blocks [256,..): node_table fp32 -> fp16 grid-stride convert
__global__ __launch_bounds__(256) void pgra_prep(
    const float* __restrict__ node_table, __half* __restrict__ nt16, int n8,
    const float* __restrict__ rela, float* __restrict__ costab)
{
    if (blockIdx.x < 256) {
        const int pair = blockIdx.x * 4 + (threadIdx.x >> 6);
        const int lane = threadIdx.x & 63;
        const int r = pair >> 5, c = pair & 31;
        const float2 av = ((const float2*)(rela + (size_t)r * EMB))[lane];
        const float2 bv = ((const float2*)(rela + (size_t)c * EMB))[lane];
        float dot = av.x * bv.x + av.y * bv.y;
        float na  = av.x * av.x + av.y * av.y;
        float nb  = bv.x * bv.x + bv.y * bv.y;
        #pragma unroll
        for (int off = 32; off > 0; off >>= 1) {
            dot += __shfl_xor(dot, off);
            na  += __shfl_xor(na,  off);
            nb  += __shfl_xor(nb,  off);
        }
        if (lane == 0)
            costab[pair] = fabsf(dot / (sqrtf(na) * sqrtf(nb) + 1e-8f));
        return;
    }
    union { __half2 h; unsigned u; } c0, c1, c2, c3;
    const int stride = (gridDim.x - 256) * 256;
    for (int i = (blockIdx.x - 256) * 256 + threadIdx.x; i < n8; i += stride) {
        const float4 a = ((const float4*)node_table)[2 * i];
        const float4 b = ((const float4*)node_table)[2 * i + 1];
        c0.h = __float22half2_rn(make_float2(a.x, a.y));
        c1.h = __float22half2_rn(make_float2(a.z, a.w));
        c2.h = __float22half2_rn(make_float2(b.x, b.y));
        c3.h = __float22half2_rn(make_float2(b.z, b.w));
        uint4 o; o.x = c0.u; o.y = c1.u; o.z = c2.u; o.w = c3.u;
        ((uint4*)nt16)[i] = o;
    }
}

// ---------------- Kernel A: fp16 gather, one (b,j) per wave (r12 verified) --
// Regular (cached) loads — NT loads measured 8 us slower (r14).
__global__ __launch_bounds__(256) void pgra_gather7(
    const int* __restrict__ node, const int* __restrict__ relation,
    const int* __restrict__ adj_node, const int* __restrict__ adj_rela,
    const __half* __restrict__ nt16, const float* __restrict__ proj_table,
    const float* __restrict__ costab, float* __restrict__ agg, int npair)
{
    const int p = blockIdx.x * 4 + (threadIdx.x >> 6);
    if (p >= npair) return;
    const int lane = threadIdx.x & 63;
    const int b = p >> 4, j = p & 15;

    const int n0  = node[b];
    const int rel = relation[b];
    const int n1  = adj_node[n0 * KN + j];

    const int4* n2p = (const int4*)(adj_node + (size_t)n1 * KN);
    const int4* r1p = (const int4*)(adj_rela + (size_t)n1 * KN);
    const int4 nn0 = n2p[0], nn1 = n2p[1], nn2 = n2p[2], nn3 = n2p[3];
    const int4 rr0 = r1p[0], rr1 = r1p[1], rr2 = r1p[2], rr3 = r1p[3];

    // ---- issue all 16 row loads (half2 per lane = 1 VGPR each) ----
    __half2 h0,h1,h2,h3,h4,h5,h6,h7,h8,h9,h10,h11,h12,h13,h14,h15;
    h0  = ((const __half2*)(nt16 + (size_t)nn0.x * EMB))[lane];
    h1  = ((const __half2*)(nt16 + (size_t)nn0.y * EMB))[lane];
    h2  = ((const __half2*)(nt16 + (size_t)nn0.z * EMB))[lane];
    h3  = ((const __half2*)(nt16 + (size_t)nn0.w * EMB))[lane];
    h4  = ((const __half2*)(nt16 + (size_t)nn1.x * EMB))[lane];
    h5  = ((const __half2*)(nt16 + (size_t)nn1.y * EMB))[lane];
    h6  = ((const __half2*)(nt16 + (size_t)nn1.z * EMB))[lane];
    h7  = ((const __half2*)(nt16 + (size_t)nn1.w * EMB))[lane];
    h8  = ((const __half2*)(nt16 + (size_t)nn2.x * EMB))[lane];
    h9  = ((const __half2*)(nt16 + (size_t)nn2.y * EMB))[lane];
    h10 = ((const __half2*)(nt16 + (size_t)nn2.z * EMB))[lane];
    h11 = ((const __half2*)(nt16 + (size_t)nn2.w * EMB))[lane];
    h12 = ((const __half2*)(nt16 + (size_t)nn3.x * EMB))[lane];
    h13 = ((const __half2*)(nt16 + (size_t)nn3.y * EMB))[lane];
    h14 = ((const __half2*)(nt16 + (size_t)nn3.z * EMB))[lane];
    h15 = ((const __half2*)(nt16 + (size_t)nn3.w * EMB))[lane];
    __builtin_amdgcn_sched_barrier(0);

    // ---- scores + softmax while the row loads are in flight ----
    float sc[KN];
    sc[0]  = costab[rr0.x * NREL + rel]; sc[1]  = costab[rr0.y * NREL + rel];
    sc[2]  = costab[rr0.z * NREL + rel]; sc[3]  = costab[rr0.w * NREL + rel];
    sc[4]  = costab[rr1.x * NREL + rel]; sc[5]  = costab[rr1.y * NREL + rel];
    sc[6]  = costab[rr1.z * NREL + rel]; sc[7]  = costab[rr1.w * NREL + rel];
    sc[8]  = costab[rr2.x * NREL + rel]; sc[9]  = costab[rr2.y * NREL + rel];
    sc[10] = costab[rr2.z * NREL + rel]; sc[11] = costab[rr2.w * NREL + rel];
    sc[12] = costab[rr3.x * NREL + rel]; sc[13] = costab[rr3.y * NREL + rel];
    sc[14] = costab[rr3.z * NREL + rel]; sc[15] = costab[rr3.w * NREL + rel];

    float m = sc[0];
    #pragma unroll
    for (int k = 1; k < KN; ++k) m = fmaxf(m, sc[k]);
    float sum = 0.f;
    #pragma unroll
    for (int k = 0; k < KN; ++k) { sc[k] = __expf(sc[k] - m); sum += sc[k]; }
    const float inv = __fdividef(1.f, sum);

    // ---- weighted sum over prefetched rows ----
    float ax = 0.f, ay = 0.f;
    float2 v;
    v = __half22float2(h0);  ax = fmaf(sc[0],  v.x, ax); ay = fmaf(sc[0],  v.y, ay);
    v = __half22float2(h1);  ax = fmaf(sc[1],  v.x, ax); ay = fmaf(sc[1],  v.y, ay);
    v = __half22float2(h2);  ax = fmaf(sc[2],  v.x, ax); ay = fmaf(sc[2],  v.y, ay);
    v = __half22float2(h3);  ax = fmaf(sc[3],  v.x, ax); ay = fmaf(sc[3],  v.y, ay);
    v = __half22float2(h4);  ax = fmaf(sc[4],  v.x, ax); ay = fmaf(sc[4],  v.y, ay);
    v = __half22float2(h5);  ax = fmaf(sc[5],  v.x, ax); ay = fmaf(sc[5],  v.y, ay);
    v = __half22float2(h6);  ax = fmaf(sc[6],  v.x, ax); ay = fmaf(sc[6],  v.y, ay);
    v = __half22float2(h7);  ax = fmaf(sc[7],  v.x, ax); ay = fmaf(sc[7],  v.y, ay);
    v = __half22float2(h8);  ax = fmaf(sc[8],  v.x, ax); ay = fmaf(sc[8],  v.y, ay);
    v = __half22float2(h9);  ax = fmaf(sc[9],  v.x, ax); ay = fmaf(sc[9],  v.y, ay);
    v = __half22float2(h10); ax = fmaf(sc[10], v.x, ax); ay = fmaf(sc[10], v.y, ay);
    v = __half22float2(h11); ax = fmaf(sc[11], v.x, ax); ay = fmaf(sc[11], v.y, ay);
    v = __half22float2(h12); ax = fmaf(sc[12], v.x, ax); ay = fmaf(sc[12], v.y, ay);
    v = __half22float2(h13); ax = fmaf(sc[13], v.x, ax); ay = fmaf(sc[13], v.y, ay);
    v = __half22float2(h14); ax = fmaf(sc[14], v.x, ax); ay = fmaf(sc[14], v.y, ay);
    v = __half22float2(h15); ax = fmaf(sc[15], v.x, ax); ay = fmaf(sc[15], v.y, ay);

    const float2 pj = ((const float2*)(proj_table + (size_t)rel * EMB))[lane];
    float2 o;
    o.x = ax * inv * pj.x;
    o.y = ay * inv * pj.y;
    ((float2*)(agg + (size_t)p * EMB))[lane] = o;
}

// ---------------- Kernel B: tail11 (r11/r12 verified, half-wave k-split) ----
__global__ __launch_bounds__(256) void pgra_tail11(
    const int* __restrict__ node, const int* __restrict__ relation,
    const int* __restrict__ adj_rela, const float* __restrict__ agg,
    const float* __restrict__ W0, const float* __restrict__ b0,
    const float* __restrict__ W1, const float* __restrict__ b1,
    const float* __restrict__ costab, float* __restrict__ out)
{
    const int blk  = blockIdx.x;
    const int tid  = threadIdx.x;
    const int wave = tid >> 6;
    const int lane = tid & 63;
    const int h    = lane >> 5;
    const int c    = lane & 31;
    const int b    = blk * 4 + wave;

    __shared__ float s_agg[4][KN][EMB];
    __shared__ float s_fin[4][EMB];

    {
        const float4* ap = (const float4*)(agg + (size_t)blk * 4 * KN * EMB);
        float4* sp = (float4*)&s_agg[0][0][0];
        #pragma unroll
        for (int q = 0; q < 8; ++q) sp[tid + 256 * q] = ap[tid + 256 * q];
    }

    const int n0  = node[b];
    const int rel = relation[b];

    float sc0[KN];
    {
        const int4* r0p = (const int4*)(adj_rela + (size_t)n0 * KN);
        #pragma unroll
        for (int q = 0; q < 4; ++q) {
            const int4 rr = r0p[q];
            sc0[4*q+0] = costab[rr.x * NREL + rel];
            sc0[4*q+1] = costab[rr.y * NREL + rel];
            sc0[4*q+2] = costab[rr.z * NREL + rel];
            sc0[4*q+3] = costab[rr.w * NREL + rel];
        }
    }
    float m = sc0[0];
    #pragma unroll
    for (int k = 1; k < KN; ++k) m = fmaxf(m, sc0[k]);
    float sum = 0.f;
    #pragma unroll
    for (int k = 0; k < KN; ++k) { sc0[k] = __expf(sc0[k] - m); sum += sc0[k]; }
    const float inv = __fdividef(1.f, sum);

    __syncthreads();

    float4 acc[8];
    const float4 bias = *(const float4*)&b0[4 * c];
    #pragma unroll
    for (int kk = 0; kk < 8; ++kk) acc[kk] = bias;

    for (int ee4 = 0; ee4 < 32; ++ee4) {
        const int row = 4 * ee4;
        float4 w0q[4];
        #pragma unroll
        for (int r = 0; r < 4; ++r)
            w0q[r] = *(const float4*)&W0[(row + r) * EMB + 4 * c];
        #pragma unroll
        for (int kk = 0; kk < 8; ++kk) {
            const float4 a = *(const float4*)&s_agg[wave][8 * h + kk][row];
            acc[kk] = fma4(a.x, w0q[0], fma4(a.y, w0q[1],
                      fma4(a.z, w0q[2], fma4(a.w, w0q[3], acc[kk]))));
        }
    }

    float4 part = make_float4(0.f, 0.f, 0.f, 0.f);
    #pragma unroll
    for (int kk = 0; kk < 8; ++kk) {
        const float w = sc0[8 * h + kk] * inv;
        part.x = fmaf(w, fast_tanh(acc[kk].x), part.x);
        part.y = fmaf(w, fast_tanh(acc[kk].y), part.y);
        part.z = fmaf(w, fast_tanh(acc[kk].z), part.z);
        part.w = fmaf(w, fast_tanh(acc[kk].w), part.w);
    }
    part.x += __shfl_xor(part.x, 32);
    part.y += __shfl_xor(part.y, 32);
    part.z += __shfl_xor(part.z, 32);
    part.w += __shfl_xor(part.w, 32);
    if (h == 0) *(float4*)&s_fin[wave][4 * c] = part;
    __syncthreads();

    float4 o = make_float4(0.f, 0.f, 0.f, 0.f);
    for (int i = 0; i < 16; ++i) {
        const int row = 64 * h + 4 * i;
        const float4 f = *(const float4*)&s_fin[wave][row];
        float4 w1q[4];
        #pragma unroll
        for (int r = 0; r < 4; ++r)
            w1q[r] = *(const float4*)&W1[(row + r) * EMB + 4 * c];
        o = fma4(f.x, w1q[0], fma4(f.y, w1q[1],
            fma4(f.z, w1q[2], fma4(f.w, w1q[3], o))));
    }
    o.x += __shfl_xor(o.x, 32);
    o.y += __shfl_xor(o.y, 32);
    o.z += __shfl_xor(o.z, 32);
    o.w += __shfl_xor(o.w, 32);
    if (h == 0) {
        const float4 bb = *(const float4*)&b1[4 * c];
        float4 r;
        r.x = fast_tanh(o.x + bb.x);
        r.y = fast_tanh(o.y + bb.y);
        r.z = fast_tanh(o.z + bb.z);
        r.w = fast_tanh(o.w + bb.w);
        *(float4*)&out[(size_t)b * EMB + 4 * c] = r;
    }
}

// ---------------- Fallback: standalone costab + fused fp32 (verified) -------
__global__ __launch_bounds__(256) void pgra_costab_k(const float* __restrict__ rela,
                                                     float* __restrict__ costab) {
    const int pair = blockIdx.x * 4 + (threadIdx.x >> 6);
    const int lane = threadIdx.x & 63;
    const int r = pair >> 5, c = pair & 31;
    const float2 av = ((const float2*)(rela + (size_t)r * EMB))[lane];
    const float2 bv = ((const float2*)(rela + (size_t)c * EMB))[lane];
    float dot = av.x * bv.x + av.y * bv.y;
    float na  = av.x * av.x + av.y * av.y;
    float nb  = bv.x * bv.x + bv.y * bv.y;
    #pragma unroll
    for (int off = 32; off > 0; off >>= 1) {
        dot += __shfl_xor(dot, off);
        na  += __shfl_xor(na,  off);
        nb  += __shfl_xor(nb,  off);
    }
    if (lane == 0)
        costab[pair] = fabsf(dot / (sqrtf(na) * sqrtf(nb) + 1e-8f));
}

__global__ __launch_bounds__(1024) void pgra_fused(
    const int* __restrict__ node, const int* __restrict__ relation,
    const int* __restrict__ adj_node, const int* __restrict__ adj_rela,
    const float* __restrict__ node_table, const float* __restrict__ proj_table,
    const float* __restrict__ W0, const float* __restrict__ b0,
    const float* __restrict__ W1, const float* __restrict__ b1,
    const float* __restrict__ costab, float* __restrict__ out)
{
    const int b    = blockIdx.x;
    const int tid  = threadIdx.x;
    const int wave = tid >> 6;
    const int lane = tid & 63;

    __shared__ float s_agg[KN][EMB];
    __shared__ float s_part[2][EMB];
    __shared__ float s_fin[EMB];

    const int n0  = node[b];
    const int rel = relation[b];

    {
        const int j  = wave;
        const int n1 = adj_node[n0 * KN + j];
        const int4* n2p = (const int4*)(adj_node + (size_t)n1 * KN);
        const int4* r1p = (const int4*)(adj_rela + (size_t)n1 * KN);
        int   n2[KN];
        float sc[KN];
        #pragma unroll
        for (int q = 0; q < 4; ++q) {
            const int4 nn = n2p[q];
            const int4 rr = r1p[q];
            n2[4*q+0] = nn.x; n2[4*q+1] = nn.y; n2[4*q+2] = nn.z; n2[4*q+3] = nn.w;
            sc[4*q+0] = costab[rr.x * NREL + rel];
            sc[4*q+1] = costab[rr.y * NREL + rel];
            sc[4*q+2] = costab[rr.z * NREL + rel];
            sc[4*q+3] = costab[rr.w * NREL + rel];
        }
        float m = sc[0];
        #pragma unroll
        for (int k = 1; k < KN; ++k) m = fmaxf(m, sc[k]);
        float sum = 0.f;
        #pragma unroll
        for (int k = 0; k < KN; ++k) { sc[k] = __expf(sc[k] - m); sum += sc[k]; }
        const float inv = 1.f / sum;
        float ax = 0.f, ay = 0.f;
        #pragma unroll
        for (int k = 0; k < KN; ++k) {
            const float2 v = ((const float2*)(node_table + (size_t)n2[k] * EMB))[lane];
            ax = fmaf(sc[k], v.x, ax);
            ay = fmaf(sc[k], v.y, ay);
        }
        const float2 pj = ((const float2*)(proj_table + (size_t)rel * EMB))[lane];
        s_agg[j][2*lane]   = ax * inv * pj.x;
        s_agg[j][2*lane+1] = ay * inv * pj.y;
    }
    __syncthreads();

    if (tid < 256) {
        const int e  = tid & 127;
        const int g  = tid >> 7;
        const int jg = g * 8;
        float acc[8];
        const float bias = b0[e];
        #pragma unroll
        for (int q = 0; q < 8; ++q) acc[q] = bias;
        for (int ee4 = 0; ee4 < EMB / 4; ++ee4) {
            const float w0v = W0[(4 * ee4 + 0) * EMB + e];
            const float w1v = W0[(4 * ee4 + 1) * EMB + e];
            const float w2v = W0[(4 * ee4 + 2) * EMB + e];
            const float w3v = W0[(4 * ee4 + 3) * EMB + e];
            #pragma unroll
            for (int q = 0; q < 8; ++q) {
                const float4 a = *(const float4*)&s_agg[jg + q][4 * ee4];
                acc[q] = fmaf(a.x, w0v, fmaf(a.y, w1v, fmaf(a.z, w2v, fmaf(a.w, w3v, acc[q]))));
            }
        }
        float sc0[KN];
        float m = -1e30f;
        #pragma unroll
        for (int k = 0; k < KN; ++k) {
            sc0[k] = costab[adj_rela[n0 * KN + k] * NREL + rel];
            m = fmaxf(m, sc0[k]);
        }
        float sum = 0.f;
        #pragma unroll
        for (int k = 0; k < KN; ++k) { sc0[k] = __expf(sc0[k] - m); sum += sc0[k]; }
        const float inv = 1.f / sum;
        float part = 0.f;
        #pragma unroll
        for (int q = 0; q < 8; ++q)
            part = fmaf(sc0[jg + q] * inv, fast_tanh(acc[q]), part);
        s_part[g][e] = part;
    }
    __syncthreads();

    if (tid < EMB) s_fin[tid] = s_part[0][tid] + s_part[1][tid];
    __syncthreads();

    if (tid < EMB) {
        float acc = b1[tid];
        for (int ee = 0; ee < EMB; ++ee) acc = fmaf(s_fin[ee], W1[ee * EMB + tid], acc);
        out[(size_t)b * EMB + tid] = fast_tanh(acc);
    }
}

extern "C" void kernel_launch(void* const* d_in, const int* in_sizes, int n_in,
                              void* d_out, int out_size, void* d_ws, size_t ws_size,
                              hipStream_t stream) {
    const int*   node       = (const int*)d_in[0];
    const int*   relation   = (const int*)d_in[1];
    const int*   adj_node   = (const int*)d_in[2];
    const int*   adj_rela   = (const int*)d_in[3];
    const float* node_table = (const float*)d_in[4];
    const float* rela_table = (const float*)d_in[5];
    const float* proj_table = (const float*)d_in[6];
    const float* W0         = (const float*)d_in[7];
    const float* b0         = (const float*)d_in[8];
    const float* W1         = (const float*)d_in[9];
    const float* b1         = (const float*)d_in[10];
    float* outp = (float*)d_out;
    const int B  = in_sizes[0];
    const int NN = in_sizes[4] / EMB;

    float*  costab = (float*)d_ws;                          // 4 KB
    float*  agg    = (float*)d_ws + 1024;                   // B*16*128 fp32
    __half* nt16   = (__half*)(agg + (size_t)B * KN * EMB); // NN*128 fp16

    const size_t need = (size_t)(1024 + (size_t)B * KN * EMB) * sizeof(float)
                      + (size_t)NN * EMB * sizeof(__half);

    if (ws_size >= need && (B % 4) == 0) {
        const int n8 = NN * EMB / 8;
        hipLaunchKernelGGL(pgra_prep, dim3(256 + 2048), dim3(256), 0, stream,
                           node_table, nt16, n8, rela_table, costab);
        const int npair = B * KN;
        hipLaunchKernelGGL(pgra_gather7, dim3((npair + 3) / 4), dim3(256), 0, stream,
                           node, relation, adj_node, adj_rela,
                           nt16, proj_table, costab, agg, npair);
        hipLaunchKernelGGL(pgra_tail11, dim3(B / 4), dim3(256), 0, stream,
                           node, relation, adj_rela, agg,
                           W0, b0, W1, b1, costab, outp);
    } else {
        hipLaunchKernelGGL(pgra_costab_k, dim3(NREL * NREL / 4), dim3(256), 0, stream,
                           rela_table, costab);
        hipLaunchKernelGGL(pgra_fused, dim3(B), dim3(1024), 0, stream,
                           node, relation, adj_node, adj_rela,
                           node_table, proj_table, W0, b0, W1, b1, costab, outp);
    }
}